// Round 1
// baseline (234.743 us; speedup 1.0000x reference)
//
#include <hip/hip_runtime.h>

// Sparsemax, last dim d=1024, 32768 rows, fp32.
// TWO rows per wave, 16 register-resident elements/lane/row. ZERO LDS:
// wave reductions via DPP (row_shr + row_bcast) on VALU; counts via
// ballot+popcount on SALU. The two rows' Newton chains are independent,
// so their DPP trees / divides / reg trees interleave in the SIMD and
// double issue-slot utilization during the (otherwise serial) solve.
// Newton iteration  t' = t + (sum(relu(z-t)) - 1)/#{z>t}  from t0=max-1
// is monotone from below on the convex piecewise-linear objective and
// lands exactly on the root's linear segment (~4-6 iters).
// Divide replaced by v_rcp_f32 (n is an exact small int; ~2^-22 rel err,
// and the final Newton step -> 0, so tau error is ~1e-7 -- far inside
// the 2e-3 harness tolerance).

#define ROW_D 1024

typedef float f4 __attribute__((ext_vector_type(4)));

template <int CTRL, int RMASK>
__device__ __forceinline__ float dpp_mv(float x) {
    return __builtin_bit_cast(float, __builtin_amdgcn_update_dpp(
        __builtin_bit_cast(int, x), __builtin_bit_cast(int, x),
        CTRL, RMASK, 0xf, false));
}

// Wave64 sum -> total lands in lane 63. row_shr:k folds each 16-lane row
// into its top lane; bcast15/31 fold rows.
__device__ __forceinline__ float dpp_sum_to63(float x) {
    x += dpp_mv<0x111, 0xf>(x);   // row_shr:1
    x += dpp_mv<0x112, 0xf>(x);   // row_shr:2
    x += dpp_mv<0x114, 0xf>(x);   // row_shr:4
    x += dpp_mv<0x118, 0xf>(x);   // row_shr:8
    x += dpp_mv<0x142, 0xa>(x);   // row_bcast15 -> rows 1,3
    x += dpp_mv<0x143, 0xc>(x);   // row_bcast31 -> rows 2,3
    return x;
}
__device__ __forceinline__ float dpp_max_to63(float x) {
    x = fmaxf(x, dpp_mv<0x111, 0xf>(x));
    x = fmaxf(x, dpp_mv<0x112, 0xf>(x));
    x = fmaxf(x, dpp_mv<0x114, 0xf>(x));
    x = fmaxf(x, dpp_mv<0x118, 0xf>(x));
    x = fmaxf(x, dpp_mv<0x142, 0xa>(x));
    x = fmaxf(x, dpp_mv<0x143, 0xc>(x));
    return x;
}
__device__ __forceinline__ float bcast63(float x) {
    return __builtin_bit_cast(float,
        __builtin_amdgcn_readlane(__builtin_bit_cast(int, x), 63));
}
__device__ __forceinline__ float fast_rcp(float x) {
    float r;
    asm("v_rcp_f32 %0, %1" : "=v"(r) : "v"(x));
    return r;
}

__global__ __launch_bounds__(256) void sparsemax_kernel(
    const float* __restrict__ z, float* __restrict__ out, int nrows) {
    const int lane = (int)(threadIdx.x & 63u);
    const int wid  = (int)(blockIdx.x << 2) + (int)(threadIdx.x >> 6);
    const int rowA = wid << 1;                       // 2 adjacent rows/wave
    if (rowA >= nrows) return;
    const int rowB = (rowA + 1 < nrows) ? rowA + 1 : rowA;  // safe tail dup

    const f4* __restrict__ zA = reinterpret_cast<const f4*>(z + (size_t)rowA * ROW_D);
    const f4* __restrict__ zB = reinterpret_cast<const f4*>(z + (size_t)rowB * ROW_D);
    f4* __restrict__ pA = reinterpret_cast<f4*>(out + (size_t)rowA * ROW_D);
    f4* __restrict__ pB = reinterpret_cast<f4*>(out + (size_t)rowB * ROW_D);

    // 8 coalesced dwordx4 loads issued back-to-back: 8 KB in flight/wave.
    f4 a[4], b[4];
#pragma unroll
    for (int j = 0; j < 4; ++j) {
        a[j] = zA[lane + 64 * j];
        b[j] = zB[lane + 64 * j];
    }

    // Row maxes: pairwise reg trees, then two interleaved DPP wave-max chains.
    float mjA[4], mjB[4];
#pragma unroll
    for (int j = 0; j < 4; ++j) {
        mjA[j] = fmaxf(fmaxf(a[j].x, a[j].y), fmaxf(a[j].z, a[j].w));
        mjB[j] = fmaxf(fmaxf(b[j].x, b[j].y), fmaxf(b[j].z, b[j].w));
    }
    float mA = fmaxf(fmaxf(mjA[0], mjA[1]), fmaxf(mjA[2], mjA[3]));
    float mB = fmaxf(fmaxf(mjB[0], mjB[1]), fmaxf(mjB[2], mjB[3]));
    mA = bcast63(dpp_max_to63(mA));
    mB = bcast63(dpp_max_to63(mB));

    // Newton from below; wave-uniform everything, no divergence.
    float tA = mA - 1.0f;
    float tB = mB - 1.0f;
#pragma unroll 1
    for (int it = 0; it < 16; ++it) {
        float sjA[4], sjB[4];
        int nA = 0, nB = 0;
#pragma unroll
        for (int j = 0; j < 4; ++j) {
            const float d0 = a[j].x - tA, d1 = a[j].y - tA;
            const float d2 = a[j].z - tA, d3 = a[j].w - tA;
            sjA[j] = (fmaxf(d0, 0.0f) + fmaxf(d1, 0.0f)) +
                     (fmaxf(d2, 0.0f) + fmaxf(d3, 0.0f));
            nA += __popcll(__ballot(d0 > 0.0f));
            nA += __popcll(__ballot(d1 > 0.0f));
            nA += __popcll(__ballot(d2 > 0.0f));
            nA += __popcll(__ballot(d3 > 0.0f));
            const float e0 = b[j].x - tB, e1 = b[j].y - tB;
            const float e2 = b[j].z - tB, e3 = b[j].w - tB;
            sjB[j] = (fmaxf(e0, 0.0f) + fmaxf(e1, 0.0f)) +
                     (fmaxf(e2, 0.0f) + fmaxf(e3, 0.0f));
            nB += __popcll(__ballot(e0 > 0.0f));
            nB += __popcll(__ballot(e1 > 0.0f));
            nB += __popcll(__ballot(e2 > 0.0f));
            nB += __popcll(__ballot(e3 > 0.0f));
        }
        // Two independent DPP sum trees -- chains interleave, shared latency.
        const float SA = bcast63(dpp_sum_to63((sjA[0] + sjA[1]) + (sjA[2] + sjA[3])));
        const float SB = bcast63(dpp_sum_to63((sjB[0] + sjB[1]) + (sjB[2] + sjB[3])));
        // n >= 1 always (t stays strictly below max: root tau <= max - 1/d,
        // post-convergence drift is ~1e-7/iter over <=16 iters).
        const float stepA = (SA - 1.0f) * fast_rcp((float)nA);
        const float stepB = (SB - 1.0f) * fast_rcp((float)nB);
        tA += stepA;
        tB += stepB;
        if (fmaxf(stepA, stepB) <= 1e-6f) break;   // wave-uniform exit
    }

    // p = relu(z - tau); nontemporal: output is never re-read, keep L3 for input.
#pragma unroll
    for (int j = 0; j < 4; ++j) {
        f4 oa, ob;
        oa.x = fmaxf(a[j].x - tA, 0.0f);
        oa.y = fmaxf(a[j].y - tA, 0.0f);
        oa.z = fmaxf(a[j].z - tA, 0.0f);
        oa.w = fmaxf(a[j].w - tA, 0.0f);
        ob.x = fmaxf(b[j].x - tB, 0.0f);
        ob.y = fmaxf(b[j].y - tB, 0.0f);
        ob.z = fmaxf(b[j].z - tB, 0.0f);
        ob.w = fmaxf(b[j].w - tB, 0.0f);
        __builtin_nontemporal_store(oa, pA + lane + 64 * j);
        __builtin_nontemporal_store(ob, pB + lane + 64 * j);
    }
}

extern "C" void kernel_launch(void* const* d_in, const int* in_sizes, int n_in,
                              void* d_out, int out_size, void* d_ws, size_t ws_size,
                              hipStream_t stream) {
    const float* z = (const float*)d_in[0];
    float* out = (float*)d_out;
    const int n = in_sizes[0];            // 8*4096*1024
    const int nrows = n / ROW_D;          // 32768
    const int pairs = (nrows + 1) >> 1;   // 2 rows per wave
    const int blocks = (pairs + 3) >> 2;  // 4 waves (8 rows) per 256-thread block
    sparsemax_kernel<<<blocks, 256, 0, stream>>>(z, out, nrows);
}

// Round 2
// 231.353 us; speedup vs baseline: 1.0147x; 1.0147x over previous
//
#include <hip/hip_runtime.h>

// Sparsemax, last dim d=1024, 32768 rows, fp32.
// PERSISTENT waves + software pipeline: 8192 waves (2048 blocks, full
// machine), each wave grid-strides over 4 rows with two register buffers
// (A/B). The next row's 4 dwordx4 loads are issued BEFORE the current
// row's solve, so HBM traffic stays in flight during every Newton phase
// and the load/compute/store convoy (R0/R1's limiter: both pipes ~30%,
// anti-phase) is broken. ZERO LDS: wave reductions via DPP
// (row_shr + row_bcast) on VALU; support counts via ballot+popcount on
// SALU. Newton iteration  t' = t + (sum(relu(z-t)) - 1)/#{z>t}  from
// t0 = max-1 is monotone from below on the convex piecewise-linear
// objective and lands exactly on the root's linear segment (~4-6 iters).
// Divide via v_rcp_f32 (n is an exact small int; ~2^-22 rel err, and the
// final Newton step -> 0, so tau error ~1e-7 << 2e-3 tolerance).

#define ROW_D 1024

typedef float f4 __attribute__((ext_vector_type(4)));

template <int CTRL, int RMASK>
__device__ __forceinline__ float dpp_mv(float x) {
    return __builtin_bit_cast(float, __builtin_amdgcn_update_dpp(
        __builtin_bit_cast(int, x), __builtin_bit_cast(int, x),
        CTRL, RMASK, 0xf, false));
}

// Wave64 sum -> total lands in lane 63. row_shr:k folds each 16-lane row
// into its top lane; bcast15/31 fold rows.
__device__ __forceinline__ float dpp_sum_to63(float x) {
    x += dpp_mv<0x111, 0xf>(x);   // row_shr:1
    x += dpp_mv<0x112, 0xf>(x);   // row_shr:2
    x += dpp_mv<0x114, 0xf>(x);   // row_shr:4
    x += dpp_mv<0x118, 0xf>(x);   // row_shr:8
    x += dpp_mv<0x142, 0xa>(x);   // row_bcast15 -> rows 1,3
    x += dpp_mv<0x143, 0xc>(x);   // row_bcast31 -> rows 2,3
    return x;
}
__device__ __forceinline__ float dpp_max_to63(float x) {
    x = fmaxf(x, dpp_mv<0x111, 0xf>(x));
    x = fmaxf(x, dpp_mv<0x112, 0xf>(x));
    x = fmaxf(x, dpp_mv<0x114, 0xf>(x));
    x = fmaxf(x, dpp_mv<0x118, 0xf>(x));
    x = fmaxf(x, dpp_mv<0x142, 0xa>(x));
    x = fmaxf(x, dpp_mv<0x143, 0xc>(x));
    return x;
}
__device__ __forceinline__ float bcast63(float x) {
    return __builtin_bit_cast(float,
        __builtin_amdgcn_readlane(__builtin_bit_cast(int, x), 63));
}
__device__ __forceinline__ float fast_rcp(float x) {
    float r;
    asm("v_rcp_f32 %0, %1" : "=v"(r) : "v"(x));
    return r;
}

__device__ __forceinline__ void load_row(f4 (&v)[4], const float* __restrict__ z,
                                         int row, int lane) {
    const f4* __restrict__ p = reinterpret_cast<const f4*>(z + (size_t)row * ROW_D);
#pragma unroll
    for (int j = 0; j < 4; ++j) v[j] = p[lane + 64 * j];
}

__device__ __forceinline__ void solve_store(f4 (&v)[4], float* __restrict__ out,
                                            int row, int lane) {
    // Row max: pairwise tree in registers, then DPP wave-max.
    float mj[4];
#pragma unroll
    for (int j = 0; j < 4; ++j)
        mj[j] = fmaxf(fmaxf(v[j].x, v[j].y), fmaxf(v[j].z, v[j].w));
    float m = fmaxf(fmaxf(mj[0], mj[1]), fmaxf(mj[2], mj[3]));
    m = bcast63(dpp_max_to63(m));

    // Newton from below; wave-uniform everything, no divergence.
    float t = m - 1.0f;
#pragma unroll 1
    for (int it = 0; it < 16; ++it) {
        float sj[4];
        int n = 0;
#pragma unroll
        for (int j = 0; j < 4; ++j) {
            const float d0 = v[j].x - t, d1 = v[j].y - t;
            const float d2 = v[j].z - t, d3 = v[j].w - t;
            sj[j] = (fmaxf(d0, 0.0f) + fmaxf(d1, 0.0f)) +
                    (fmaxf(d2, 0.0f) + fmaxf(d3, 0.0f));
            n += __popcll(__ballot(d0 > 0.0f));
            n += __popcll(__ballot(d1 > 0.0f));
            n += __popcll(__ballot(d2 > 0.0f));
            n += __popcll(__ballot(d3 > 0.0f));
        }
        const float S = bcast63(dpp_sum_to63((sj[0] + sj[1]) + (sj[2] + sj[3])));
        // n >= 1 always (t stays strictly below max).
        const float step = (S - 1.0f) * fast_rcp((float)n);
        t += step;
        if (step <= 1e-6f) break;   // wave-uniform exit
    }

    // p = relu(z - tau); nontemporal: output is never re-read, keep L3 for input.
    f4* __restrict__ p = reinterpret_cast<f4*>(out + (size_t)row * ROW_D);
#pragma unroll
    for (int j = 0; j < 4; ++j) {
        f4 o;
        o.x = fmaxf(v[j].x - t, 0.0f);
        o.y = fmaxf(v[j].y - t, 0.0f);
        o.z = fmaxf(v[j].z - t, 0.0f);
        o.w = fmaxf(v[j].w - t, 0.0f);
        __builtin_nontemporal_store(o, p + lane + 64 * j);
    }
}

__global__ __launch_bounds__(256, 8) void sparsemax_kernel(
    const float* __restrict__ z, float* __restrict__ out, int nrows) {
    const int lane = (int)(threadIdx.x & 63u);
    int r = (int)(blockIdx.x << 2) + (int)(threadIdx.x >> 6);
    const int W = (int)(gridDim.x << 2);   // total waves = rows per stage
    if (r >= nrows) return;

    // Two register buffers, statically named (no runtime indexing -> no
    // scratch). Loads for the NEXT row are issued before the current
    // row's solve; the compiler's counted s_waitcnt vmcnt(N) lets them
    // stay in flight across the whole Newton phase.
    f4 A[4], B[4];
    load_row(A, z, r, lane);
    int rn = r + W;
    for (;;) {
        if (rn < nrows) load_row(B, z, rn, lane);   // prefetch (overlaps solve A)
        solve_store(A, out, r, lane);
        if (rn >= nrows) break;
        r = rn + W;
        if (r < nrows) load_row(A, z, r, lane);     // prefetch (overlaps solve B)
        solve_store(B, out, rn, lane);
        if (r >= nrows) break;
        rn = r + W;
    }
}

extern "C" void kernel_launch(void* const* d_in, const int* in_sizes, int n_in,
                              void* d_out, int out_size, void* d_ws, size_t ws_size,
                              hipStream_t stream) {
    const float* z = (const float*)d_in[0];
    float* out = (float*)d_out;
    const int n = in_sizes[0];            // 8*4096*1024
    const int nrows = n / ROW_D;          // 32768
    // Fill the machine exactly: 2048 blocks x 4 waves = 8192 persistent
    // waves (32 waves/CU on 256 CUs); each wave pipelines nrows/8192 = 4 rows.
    int blocks = 2048;
    const int max_blocks = (nrows + 3) >> 2;
    if (blocks > max_blocks) blocks = max_blocks;
    sparsemax_kernel<<<blocks, 256, 0, stream>>>(z, out, nrows);
}